// Round 1
// baseline (1611.502 us; speedup 1.0000x reference)
//
#include <hip/hip_runtime.h>

// Residual VQ, shared Euclidean codebook, Q=4 stages.
// x: [8,64,128,128] f32, codebook: [512,64] f32.
// Outputs flat in d_out (all f32): quantized [8,64,128,128] (8388608),
// indices [8,128,128,4] stored as float (524288), commit_loss [4].

#define NPTS   131072      // 8*128*128
#define CH     64
#define KCODE  512
#define NQ     4
#define HW     16384       // 128*128

__global__ __launch_bounds__(256) void rvq_kernel(
    const float* __restrict__ x, const float* __restrict__ cb,
    float* __restrict__ out_quant, float* __restrict__ out_idx,
    float* __restrict__ out_loss)
{
    __shared__ float s_csq[KCODE];
    __shared__ float s_loss[4][NQ];

    const int tid = threadIdx.x;

    // ---- precompute ||c_k||^2 into LDS (2 KB) ----
    for (int k = tid; k < KCODE; k += 256) {
        const float4* row = (const float4*)(cb + k * CH);
        float a0 = 0.f, a1 = 0.f, a2 = 0.f, a3 = 0.f;
#pragma unroll
        for (int j = 0; j < CH / 4; ++j) {
            float4 v = row[j];
            a0 = fmaf(v.x, v.x, a0); a1 = fmaf(v.y, v.y, a1);
            a2 = fmaf(v.z, v.z, a2); a3 = fmaf(v.w, v.w, a3);
        }
        s_csq[k] = (a0 + a1) + (a2 + a3);
    }
    __syncthreads();

    const int n  = blockIdx.x * 256 + tid;   // point id; grid covers exactly NPTS
    const int hw = n & (HW - 1);
    const int b  = n >> 14;                  // n / HW
    const float* xb = x + (size_t)b * CH * HW + hw;

    // residual in registers
    float r[CH];
#pragma unroll
    for (int c = 0; c < CH; ++c) r[c] = xb[(size_t)c * HW];

    float loss[NQ];
    int   idxs[NQ];

    for (int q = 0; q < NQ; ++q) {
        float best = 3.4e38f;
        int   bidx = 0;
        for (int k = 0; k < KCODE; ++k) {
            const float* row = cb + k * CH;   // wave-uniform address -> s_load
            float d0 = 0.f, d1 = 0.f, d2 = 0.f, d3 = 0.f;
#pragma unroll
            for (int c = 0; c < CH; c += 4) {
                d0 = fmaf(r[c + 0], row[c + 0], d0);
                d1 = fmaf(r[c + 1], row[c + 1], d1);
                d2 = fmaf(r[c + 2], row[c + 2], d2);
                d3 = fmaf(r[c + 3], row[c + 3], d3);
            }
            float dist = s_csq[k] - 2.0f * ((d0 + d1) + (d2 + d3));
            if (dist < best) { best = dist; bidx = k; }   // first-occurrence ties
        }
        idxs[q] = bidx;

        // subtract chosen code (divergent gather), accumulate ||r_new||^2
        const float4* rowv = (const float4*)(cb + bidx * CH);
        float l0 = 0.f, l1 = 0.f, l2 = 0.f, l3 = 0.f;
#pragma unroll
        for (int j = 0; j < CH / 4; ++j) {
            float4 v = rowv[j];
            float t0 = r[4 * j + 0] - v.x;
            float t1 = r[4 * j + 1] - v.y;
            float t2 = r[4 * j + 2] - v.z;
            float t3 = r[4 * j + 3] - v.w;
            r[4 * j + 0] = t0; r[4 * j + 1] = t1;
            r[4 * j + 2] = t2; r[4 * j + 3] = t3;
            l0 = fmaf(t0, t0, l0); l1 = fmaf(t1, t1, l1);
            l2 = fmaf(t2, t2, l2); l3 = fmaf(t3, t3, l3);
        }
        loss[q] = (l0 + l1) + (l2 + l3);
    }

    // ---- indices as float, [B,H,W,Q] == n*4+q, one float4 per point ----
    ((float4*)out_idx)[n] =
        make_float4((float)idxs[0], (float)idxs[1], (float)idxs[2], (float)idxs[3]);

    // ---- quantized = x - r_final, coalesced per channel ----
    float* ob = out_quant + (size_t)b * CH * HW + hw;
#pragma unroll
    for (int c = 0; c < CH; ++c) ob[(size_t)c * HW] = xb[(size_t)c * HW] - r[c];

    // ---- commit loss: wave shuffle-reduce -> LDS -> atomic per block ----
    const int lane = tid & 63, wave = tid >> 6;
#pragma unroll
    for (int q = 0; q < NQ; ++q) {
        float v = loss[q];
        for (int off = 32; off > 0; off >>= 1) v += __shfl_down(v, off, 64);
        if (lane == 0) s_loss[wave][q] = v;
    }
    __syncthreads();
    if (tid < NQ) {
        float v = s_loss[0][tid] + s_loss[1][tid] + s_loss[2][tid] + s_loss[3][tid];
        atomicAdd(&out_loss[tid], v * (1.0f / (float)((size_t)NPTS * CH)));
    }
}

extern "C" void kernel_launch(void* const* d_in, const int* in_sizes, int n_in,
                              void* d_out, int out_size, void* d_ws, size_t ws_size,
                              hipStream_t stream) {
    const float* x  = (const float*)d_in[0];
    const float* cb = (const float*)d_in[1];
    float* out       = (float*)d_out;
    float* out_quant = out;                    // 8388608
    float* out_idx   = out + 8388608;          // 524288
    float* out_loss  = out + 8388608 + 524288; // 4

    hipMemsetAsync(out_loss, 0, NQ * sizeof(float), stream);
    rvq_kernel<<<NPTS / 256, 256, 0, stream>>>(x, cb, out_quant, out_idx, out_loss);
}

// Round 2
// 528.597 us; speedup vs baseline: 3.0486x; 3.0486x over previous
//
#include <hip/hip_runtime.h>

// Residual VQ, Q=4 stages, fused SGEMM-style.
// x: [8,64,128,128] f32, codebook: [512,64] f32.
// d_out: quantized [8,64,128,128] (8388608 f32) | indices as float [8,128,128,4]
//        (524288) | commit_loss [4].
// d_ws: cbT [64][512] f32 (transposed codebook) + csq [512] f32.

#define NPTS   131072
#define CH     64
#define KCODE  512
#define NQ     4
#define HW     16384
#define BPTS   128       // points per block
#define BTHR   128       // threads per block (2 waves)
#define CHUNK  128       // codes staged per iteration
#define NITER  4         // KCODE / CHUNK

__device__ __forceinline__ void load_lds16(const float* g, float* l) {
    __builtin_amdgcn_global_load_lds(
        (const __attribute__((address_space(1))) void*)g,
        (__attribute__((address_space(3))) void*)l, 16, 0, 0);
}

// ---- prep: transpose codebook [512][64] -> [64][512], and csq ----
__global__ void prep_transpose(const float* __restrict__ cb, float* __restrict__ cbT) {
    int g = blockIdx.x * 256 + threadIdx.x;   // 0..32767, c fastest -> coalesced read
    int k = g >> 6, c = g & 63;
    cbT[c * KCODE + k] = cb[g];
}

__global__ void prep_csq(const float* __restrict__ cb, float* __restrict__ csq) {
    int k = blockIdx.x * 256 + threadIdx.x;
    if (k < KCODE) {
        const float4* row = (const float4*)(cb + (size_t)k * CH);
        float a0 = 0.f, a1 = 0.f, a2 = 0.f, a3 = 0.f;
#pragma unroll
        for (int j = 0; j < CH / 4; ++j) {
            float4 v = row[j];
            a0 = fmaf(v.x, v.x, a0); a1 = fmaf(v.y, v.y, a1);
            a2 = fmaf(v.z, v.z, a2); a3 = fmaf(v.w, v.w, a3);
        }
        csq[k] = (a0 + a1) + (a2 + a3);
    }
}

__global__ __launch_bounds__(BTHR) void rvq_main(
    const float* __restrict__ x, const float* __restrict__ cb,
    const float* __restrict__ cbT, const float* __restrict__ csq_g,
    float* __restrict__ out_quant, float* __restrict__ out_idx,
    float* __restrict__ out_loss)
{
    __shared__ __align__(16) float s_res[CH * BPTS];   // residual [c][p], 32 KB
    __shared__ __align__(16) float s_cb[CH * CHUNK];   // cb chunk [c][swizzled k], 32 KB
    __shared__ float s_csq[KCODE];                     // 2 KB
    __shared__ float s_rd[8 * BPTS];                   // per-cg best dist, 4 KB
    __shared__ int   s_ri[8 * BPTS];                   // per-cg best idx, 4 KB
    __shared__ float s_ls[2][NQ];

    const int tid  = threadIdx.x;
    const int cg   = tid & 7;          // code-group: 16 codes per iter
    const int pg   = tid >> 3;         // point-group: 8 points
    const int lane = tid & 63;
    const int w    = tid >> 6;         // wave id (0/1)

    const int n0  = blockIdx.x * BPTS;           // never straddles batch b
    const int b   = n0 >> 14;
    const int hw0 = n0 & (HW - 1);
    const float* xbase = x + (size_t)b * CH * HW + hw0;

    // ---- init: residual tile = x, csq into LDS ----
    for (int j = tid; j < CH * BPTS / 4; j += BTHR) {   // 2048 float4s
        int c = j >> 5, p4 = j & 31;
        float4 v = *(const float4*)(xbase + (size_t)c * HW + p4 * 4);
        *(float4*)&s_res[c * BPTS + p4 * 4] = v;
    }
    for (int j = tid; j < KCODE; j += BTHR) s_csq[j] = csq_g[j];

    float lossr[NQ];
    float idxf[NQ];

    // staging lane decomposition (swizzled dest -> permuted source)
    const int ii   = (lane & 31) >> 3;   // 0..3
    const int cgl  = lane & 7;
    const int half = lane >> 5;

    for (int q = 0; q < NQ; ++q) {
        float bestd[8]; int besti[8];
#pragma unroll
        for (int p = 0; p < 8; ++p) { bestd[p] = 3.4e38f; besti[p] = 0; }

        for (int it = 0; it < NITER; ++it) {
            const int k0 = it * CHUNK;
            __syncthreads();   // prev chunk / resid update fully consumed
            // ---- stage codebook chunk: LDS[c][i*32 + cg*4 + j] = cbT[c][k0+cg*16+i*4+j]
            // (striped so a wave's 8 cg-lanes span all 32 banks on reads)
#pragma unroll
            for (int r = 0; r < 16; ++r) {
                int c = (w * 16 + r) * 2;   // wave-uniform; lanes fill rows c, c+1
                const float* gp = cbT + (size_t)(c + half) * KCODE + k0 + cgl * 16 + ii * 4;
                load_lds16(gp, &s_cb[c * CHUNK]);
            }
            __syncthreads();   // drains vmcnt before barrier

            // ---- GEMM: 8 points x 16 codes per thread over 64 channels ----
            float acc[8][16];
#pragma unroll
            for (int p = 0; p < 8; ++p)
#pragma unroll
                for (int n = 0; n < 16; ++n) acc[p][n] = 0.f;

#pragma unroll 2
            for (int c = 0; c < CH; ++c) {
                const float* br = &s_cb[c * CHUNK + cg * 4];
                float4 b0 = *(const float4*)&br[0];
                float4 b1 = *(const float4*)&br[32];
                float4 b2 = *(const float4*)&br[64];
                float4 b3 = *(const float4*)&br[96];
                const float* ar = &s_res[c * BPTS + pg * 8];
                float4 a0 = *(const float4*)&ar[0];
                float4 a1 = *(const float4*)&ar[4];
                float av[8] = {a0.x, a0.y, a0.z, a0.w, a1.x, a1.y, a1.z, a1.w};
                float bv[16] = {b0.x, b0.y, b0.z, b0.w, b1.x, b1.y, b1.z, b1.w,
                                b2.x, b2.y, b2.z, b2.w, b3.x, b3.y, b3.z, b3.w};
#pragma unroll
                for (int p = 0; p < 8; ++p)
#pragma unroll
                    for (int n = 0; n < 16; ++n)
                        acc[p][n] = fmaf(av[p], bv[n], acc[p][n]);
            }

            // ---- fused argmin update (k ascending within thread -> first-min ties) ----
            float cq[16];
#pragma unroll
            for (int n = 0; n < 16; ++n) {
                int i = n >> 2, j = n & 3;
                cq[n] = s_csq[k0 + cg * 16 + i * 4 + j];
            }
#pragma unroll
            for (int p = 0; p < 8; ++p) {
#pragma unroll
                for (int n = 0; n < 16; ++n) {
                    int i = n >> 2, j = n & 3;
                    int k = k0 + cg * 16 + i * 4 + j;
                    float d = cq[n] - 2.0f * acc[p][n];
                    if (d < bestd[p]) { bestd[p] = d; besti[p] = k; }
                }
            }
        }

        // ---- cross-cg argmin merge ----
#pragma unroll
        for (int p = 0; p < 8; ++p) {
            s_rd[cg * BPTS + pg * 8 + p] = bestd[p];
            s_ri[cg * BPTS + pg * 8 + p] = besti[p];
        }
        __syncthreads();
        float bd = 3.4e38f; int bi = 0;
#pragma unroll
        for (int g2 = 0; g2 < 8; ++g2) {
            float d = s_rd[g2 * BPTS + tid];
            int  ki = s_ri[g2 * BPTS + tid];
            if (d < bd || (d == bd && ki < bi)) { bd = d; bi = ki; }
        }
        idxf[q] = (float)bi;

        // ---- residual update for point `tid` + commit loss (sum r_new^2) ----
        const float4* crow = (const float4*)(cb + (size_t)bi * CH);
        float l0 = 0.f, l1 = 0.f, l2 = 0.f, l3 = 0.f;
#pragma unroll
        for (int c4 = 0; c4 < 16; ++c4) {
            float4 v = crow[c4];
            int c = c4 * 4;
            float r0 = s_res[(c + 0) * BPTS + tid] - v.x;
            float r1 = s_res[(c + 1) * BPTS + tid] - v.y;
            float r2 = s_res[(c + 2) * BPTS + tid] - v.z;
            float r3 = s_res[(c + 3) * BPTS + tid] - v.w;
            s_res[(c + 0) * BPTS + tid] = r0;
            s_res[(c + 1) * BPTS + tid] = r1;
            s_res[(c + 2) * BPTS + tid] = r2;
            s_res[(c + 3) * BPTS + tid] = r3;
            l0 = fmaf(r0, r0, l0); l1 = fmaf(r1, r1, l1);
            l2 = fmaf(r2, r2, l2); l3 = fmaf(r3, r3, l3);
        }
        lossr[q] = (l0 + l1) + (l2 + l3);
        __syncthreads();   // resid update visible before next stage / output
    }

    // ---- quantized = x - r_final ----
    const size_t obase = (size_t)b * CH * HW + hw0;
    for (int j = tid; j < CH * BPTS / 4; j += BTHR) {
        int c = j >> 5, p4 = j & 31;
        float4 xv = *(const float4*)(xbase + (size_t)c * HW + p4 * 4);
        float4 rv = *(const float4*)&s_res[c * BPTS + p4 * 4];
        float4 o = make_float4(xv.x - rv.x, xv.y - rv.y, xv.z - rv.z, xv.w - rv.w);
        *(float4*)(out_quant + obase + (size_t)c * HW + p4 * 4) = o;
    }

    // ---- indices (as float), one float4 per point ----
    ((float4*)out_idx)[n0 + tid] = make_float4(idxf[0], idxf[1], idxf[2], idxf[3]);

    // ---- commit loss reduction ----
#pragma unroll
    for (int qq = 0; qq < NQ; ++qq) {
        float v = lossr[qq];
        for (int off = 32; off > 0; off >>= 1) v += __shfl_down(v, off, 64);
        if (lane == 0) s_ls[w][qq] = v;
    }
    __syncthreads();
    if (tid < NQ)
        atomicAdd(&out_loss[tid],
                  (s_ls[0][tid] + s_ls[1][tid]) * (1.0f / ((float)NPTS * (float)CH)));
}

extern "C" void kernel_launch(void* const* d_in, const int* in_sizes, int n_in,
                              void* d_out, int out_size, void* d_ws, size_t ws_size,
                              hipStream_t stream) {
    const float* x  = (const float*)d_in[0];
    const float* cb = (const float*)d_in[1];
    float* out       = (float*)d_out;
    float* out_quant = out;                    // 8388608
    float* out_idx   = out + 8388608;          // 524288
    float* out_loss  = out + 8388608 + 524288; // 4

    float* cbT = (float*)d_ws;                 // 64*512 floats
    float* csq = cbT + CH * KCODE;             // 512 floats

    hipMemsetAsync(out_loss, 0, NQ * sizeof(float), stream);
    prep_transpose<<<(KCODE * CH) / 256, 256, 0, stream>>>(cb, cbT);
    prep_csq<<<2, 256, 0, stream>>>(cb, csq);
    rvq_main<<<NPTS / BPTS, BTHR, 0, stream>>>(x, cb, cbT, csq,
                                               out_quant, out_idx, out_loss);
}